// Round 12
// baseline (63.473 us; speedup 1.0000x reference)
//
#include <hip/hip_runtime.h>
#include <math.h>

#define Cc 96
#define Hh 128
#define Ww 128
#define HWsz (Hh*Ww)
#define TW 16
#define TH 8
#define LROW 18
#define LPLANE 180
#define CPAD 104      // ushort stride per position: 208B rows, 16B-aligned

typedef _Float16 h2 __attribute__((ext_vector_type(2)));
typedef short    s8v __attribute__((ext_vector_type(8)));   // 8 bf16 (MFMA A/B frag)
typedef float    f4v __attribute__((ext_vector_type(4)));   // MFMA C/D frag

__device__ __forceinline__ unsigned pkrtz_u(float a, float b) {
    return __builtin_bit_cast(unsigned, __builtin_amdgcn_cvt_pkrtz(a, b));
}
__device__ __forceinline__ h2 pk2(float a, float b) {
    return __builtin_bit_cast(h2, __builtin_amdgcn_cvt_pkrtz(a, b));
}
__device__ __forceinline__ h2 u2h(unsigned u) { return __builtin_bit_cast(h2, u); }
__device__ __forceinline__ unsigned cvt_pk_bf16(float lo, float hi) {
    unsigned r;
    asm("v_cvt_pk_bf16_f32 %0, %1, %2" : "=v"(r) : "v"(lo), "v"(hi));
    return r;
}

__host__ __device__ __forceinline__ unsigned f2bf(float f) {   // fp32 -> bf16 RNE
    unsigned u = __float_as_uint(f);
    return (u + 0x7fffu + ((u >> 16) & 1u)) >> 16;
}

#define GETW(v, wi) ((wi)==0 ? (v).x : (wi)==1 ? (v).y : (wi)==2 ? (v).z : (v).w)

// ---- d_ws layout (dword offsets) ----
#define OFF_WDW 0
#define OFF_W2  480
#define OFF_P1B 704
#define OFF_A   768
#define NPK     3072
#define WLDS_N  752

__global__ void alpf_prep(const float* __restrict__ dw_w, const float* __restrict__ dw_b,
                          const float* __restrict__ pw1_w, const float* __restrict__ pw1_b,
                          const float* __restrict__ pw2_w, unsigned* __restrict__ wpk)
{
    int i = blockIdx.x * 256 + threadIdx.x;
    if (i >= NPK) return;
    unsigned v = 0u;
    if (i < OFF_W2) {
        int g = i / 120, rem = i % 120, ks = rem / 40, s = rem % 40;
        int chb = 32*ks + 8*g;
        if (s < 4) v = pkrtz_u(dw_b[chb + 2*s], dw_b[chb + 2*s + 1]);
        else { int t = (s - 4) / 4, d = (s - 4) % 4;
               v = pkrtz_u(dw_w[(chb + 2*d)*9 + t], dw_w[(chb + 2*d + 1)*9 + t]); }
    } else if (i < OFF_P1B) {
        int idx = i - OFF_W2; int g = idx / 56, s = idx % 56;
        if (s < 54) { int k = s / 6, mm = s % 6, m = mm / 2, rp = mm % 2;
            int o = 16*m + 4*g + 2*rp;
            v = pkrtz_u(pw2_w[k*48 + o], pw2_w[k*48 + o + 1]); }
    } else if (i < OFF_P1B + 48) {
        v = __float_as_uint(pw1_b[i - OFF_P1B]);
    } else if (i >= OFF_A) {
        int idx = i - OFF_A; int f = idx / 256, rem = idx % 256, l = rem / 4, d = rem % 4;
        int m = f / 3, ks = f % 3;
        int o  = 16*m + (l & 15);
        int ch = 32*ks + 8*(l >> 4) + 2*d;
        v = f2bf(pw1_w[o*Cc + ch]) | (f2bf(pw1_w[o*Cc + ch + 1]) << 16);
    }
    wpk[i] = v;
}

__global__ __launch_bounds__(256, 4)
void alpf_fused(const float* __restrict__ x,
                const float* __restrict__ pw2_b,
                const unsigned* __restrict__ wpk,
                float* __restrict__ out)
{
    __shared__ unsigned short lx[LPLANE * CPAD];   // 37440 B
    __shared__ unsigned wlds[WLDS_N];              // 3008 B weight cache

    const int tid = threadIdx.x;

    // ---- XCD-chunked swizzle (bijective: nwg = 1024, divisible by 8) ----
    const int nwg   = gridDim.x;
    const int chunk = nwg >> 3;
    const int logical = (blockIdx.x & 7) * chunk + (blockIdx.x >> 3);
    const int tx = logical & 7;             // 8 tiles in x
    const int ty = (logical >> 3) & 15;     // 16 tiles in y
    const int b  = logical >> 7;            // batch
    const int x0 = tx * TW;
    const int y0 = ty * TH;
    const float* __restrict__ xb = x + (size_t)b * Cc * HWsz;

    // ---- weight cache copy (752 dwords = 188 uint4) ----
    if (tid < 188)
        *reinterpret_cast<uint4*>(&wlds[tid * 4]) =
            *reinterpret_cast<const uint4*>(wpk + tid * 4);

    const int lane = tid & 63;
    const int g    = lane >> 4;
    const int c15  = lane & 15;
    const int wv   = tid >> 6;              // 0..3

    // ---- resident W1 A-fragments ----
    s8v Af[9];
    #pragma unroll
    for (int f = 0; f < 9; ++f)
        Af[f] = __builtin_bit_cast(s8v,
            *reinterpret_cast<const uint4*>(wpk + OFF_A + (f*64 + lane)*4));

    // ---- slice staging lambdas: slice s = channels [32s, 32s+32) ----
    // task u in [0,320): ri = u>>5 (halo row), cp = (u&31)>>1 (ch pair in slice),
    // ph = u&1 (x half). Thread tid owns u=tid; threads 0..63 also own u=tid+256.
    auto ldtask = [&](int u, int s, float4& a0, float4& a1, float4& b0, float4& b1,
                      float& ea, float& eb) {
        const int ri = u >> 5, rem = u & 31, cp = rem >> 1, ph = rem & 1;
        const int gy = y0 - 1 + ri;
        const bool okr = (gy >= 0) & (gy < Hh);
        const int gyc = okr ? gy : 0;
        const int chA = 32*s + 2*cp;
        const float* pA = xb + (size_t)chA * HWsz + gyc * Ww + x0 + 8 * ph;
        const float* pB = pA + HWsz;
        a0 = *reinterpret_cast<const float4*>(pA);
        a1 = *reinterpret_cast<const float4*>(pA + 4);
        b0 = *reinterpret_cast<const float4*>(pB);
        b1 = *reinterpret_cast<const float4*>(pB + 4);
        if (!okr) { a0 = make_float4(0,0,0,0); a1 = a0; b0 = a0; b1 = a0; }
        const int ecol  = ph ? (x0 + 16) : (x0 - 1);
        const bool oke  = okr & (ecol >= 0) & (ecol < Ww);
        const int ecolc = (ecol >= 0 && ecol < Ww) ? ecol : 0;
        const float* pE = xb + (size_t)chA * HWsz + gyc * Ww + ecolc;
        ea = pE[0]; eb = pE[HWsz];
        if (!oke) { ea = 0.f; eb = 0.f; }
    };
    auto wrtask = [&](int u, int s, const float4& a0, const float4& a1,
                      const float4& b0, const float4& b1, float ea, float eb) {
        const int ri = u >> 5, rem = u & 31, cp = rem >> 1, ph = rem & 1;
        const int chA = 32*s + 2*cp;
        const int prow = ri * LROW + 1 + 8 * ph;
        #define STG(q, va, vb) \
            *reinterpret_cast<unsigned*>(&lx[(prow + (q)) * CPAD + chA]) = pkrtz_u(va, vb)
        STG(0, a0.x, b0.x); STG(1, a0.y, b0.y); STG(2, a0.z, b0.z); STG(3, a0.w, b0.w);
        STG(4, a1.x, b1.x); STG(5, a1.y, b1.y); STG(6, a1.z, b1.z); STG(7, a1.w, b1.w);
        #undef STG
        const int eq = ri * LROW + (ph ? 17 : 0);
        *reinterpret_cast<unsigned*>(&lx[eq * CPAD + chA]) = pkrtz_u(ea, eb);
    };

    // ---- pw1 bias -> accumulators (D rows: o = 16m + 4g + r) ----
    f4v acc[3][2];

    // staged-value registers (task tid; and task tid+256 for tid<64)
    float4 A0, A1, B0, B1; float EA, EB;
    float4 C0, C1, D0, D1; float EC, ED;
    const bool two = (tid < 64);

    // ---- prologue: stage slice 0 (exposed) ----
    ldtask(tid, 0, A0, A1, B0, B1, EA, EB);
    if (two) ldtask(tid + 256, 0, C0, C1, D0, D1, EC, ED);
    wrtask(tid, 0, A0, A1, B0, B1, EA, EB);
    if (two) wrtask(tid + 256, 0, C0, C1, D0, D1, EC, ED);
    __syncthreads();

    #pragma unroll
    for (int m = 0; m < 3; ++m) {
        const f4v bb = *reinterpret_cast<const f4v*>(&wlds[OFF_P1B + 16*m + 4*g]);
        acc[m][0] = bb;
        acc[m][1] = bb;
    }

    // ---- pipelined ks loop: issue loads(ks+1) -> compute(ks) -> write(ks+1) -> bar ----
    #pragma unroll
    for (int ks = 0; ks < 3; ++ks) {
        if (ks < 2) {
            ldtask(tid, ks + 1, A0, A1, B0, B1, EA, EB);
            if (two) ldtask(tid + 256, ks + 1, C0, C1, D0, D1, EC, ED);
        }
        // compute ks-slice: depthwise conv (f16) -> bf16 B-frag -> 6 MFMA
        {
            const int base = (g*3 + ks) * 40;
            const uint4 wb = *reinterpret_cast<const uint4*>(&wlds[base]);
            uint4 wt[9];
            #pragma unroll
            for (int t = 0; t < 9; ++t)
                wt[t] = *reinterpret_cast<const uint4*>(&wlds[base + 4 + 4*t]);
            #pragma unroll
            for (int n = 0; n < 2; ++n) {
                h2 b0 = u2h(wb.x), b1 = u2h(wb.y), b2 = u2h(wb.z), b3 = u2h(wb.w);
                #pragma unroll
                for (int t = 0; t < 9; ++t) {
                    const int dy = t / 3, dx = t - 3*dy;
                    const uint4 xv = *reinterpret_cast<const uint4*>(
                        &lx[((2*wv + n + dy)*LROW + c15 + dx)*CPAD + 32*ks + 8*g]);
                    b0 = __builtin_elementwise_fma(u2h(xv.x), u2h(wt[t].x), b0);
                    b1 = __builtin_elementwise_fma(u2h(xv.y), u2h(wt[t].y), b1);
                    b2 = __builtin_elementwise_fma(u2h(xv.z), u2h(wt[t].z), b2);
                    b3 = __builtin_elementwise_fma(u2h(xv.w), u2h(wt[t].w), b3);
                }
                uint4 bq;
                bq.x = cvt_pk_bf16((float)b0.x, (float)b0.y);
                bq.y = cvt_pk_bf16((float)b1.x, (float)b1.y);
                bq.z = cvt_pk_bf16((float)b2.x, (float)b2.y);
                bq.w = cvt_pk_bf16((float)b3.x, (float)b3.y);
                const s8v Bf = __builtin_bit_cast(s8v, bq);
                acc[0][n] = __builtin_amdgcn_mfma_f32_16x16x32_bf16(Af[0 + ks], Bf, acc[0][n], 0, 0, 0);
                acc[1][n] = __builtin_amdgcn_mfma_f32_16x16x32_bf16(Af[3 + ks], Bf, acc[1][n], 0, 0, 0);
                acc[2][n] = __builtin_amdgcn_mfma_f32_16x16x32_bf16(Af[6 + ks], Bf, acc[2][n], 0, 0, 0);
            }
        }
        if (ks < 2) {
            wrtask(tid, ks + 1, A0, A1, B0, B1, EA, EB);
            if (two) wrtask(tid + 256, ks + 1, C0, C1, D0, D1, EC, ED);
            __syncthreads();
        }
    }

    // ---- LeakyReLU + pack t to f16 pairs (o = 16m+4g+2rp, +1) ----
    h2 tpk[2][3][2];
    #pragma unroll
    for (int n = 0; n < 2; ++n)
        #pragma unroll
        for (int m = 0; m < 3; ++m)
            #pragma unroll
            for (int rp = 0; rp < 2; ++rp) {
                float a = acc[m][n][2*rp], c = acc[m][n][2*rp + 1];
                a = (a >= 0.f) ? a : 0.2f * a;
                c = (c >= 0.f) ? c : 0.2f * c;
                tpk[n][m][rp] = pk2(a, c);
            }

    // ---- pw2 partials (this lane's o-slice), then butterfly over g ----
    uint4 w2q[14];
    #pragma unroll
    for (int j = 0; j < 14; ++j)
        w2q[j] = *reinterpret_cast<const uint4*>(&wlds[OFF_W2 + g*56 + 4*j]);

    float kwr[2][9];
    #pragma unroll
    for (int k = 0; k < 9; ++k) {
        #pragma unroll
        for (int n = 0; n < 2; ++n) {
            h2 s = pk2(0.f, 0.f);
            #pragma unroll
            for (int m = 0; m < 3; ++m)
                #pragma unroll
                for (int rp = 0; rp < 2; ++rp) {
                    const int d = k*6 + 2*m + rp;
                    s = __builtin_elementwise_fma(tpk[n][m][rp],
                                                  u2h(GETW(w2q[d >> 2], d & 3)), s);
                }
            kwr[n][k] = (float)s.x + (float)s.y;
        }
    }
    #pragma unroll
    for (int n = 0; n < 2; ++n)
        #pragma unroll
        for (int k = 0; k < 9; ++k) {
            float v = kwr[n][k];
            v += __shfl_xor(v, 16);
            v += __shfl_xor(v, 32);
            kwr[n][k] = v + pw2_b[k];
        }

    // ---- pass 2 mapping: lane = 2 rows x 16 cols x 2 channel-halves ----
    const int nn  = (lane >> 4) & 1;        // row within wave's pair
    const int chh = lane >> 5;              // channel half (0: ch 0-47, 1: ch 48-95)
    const int row = 2*wv + nn;

    float kw[9];
    #pragma unroll
    for (int k = 0; k < 9; ++k) kw[k] = nn ? kwr[1][k] : kwr[0][k];

    // ---- softmax over 9 ----
    float mx = kw[0];
    #pragma unroll
    for (int k = 1; k < 9; ++k) mx = fmaxf(mx, kw[k]);
    float sum = 0.f;
    #pragma unroll
    for (int k = 0; k < 9; ++k) { kw[k] = __expf(kw[k] - mx); sum += kw[k]; }
    const float inv = 1.f / sum;
    h2 kwp[9];
    #pragma unroll
    for (int k = 0; k < 9; ++k) { kw[k] *= inv; kwp[k] = pk2(kw[k], kw[k]); }

    // ---- pass 2: smoothing; this lane covers 48 channels of its pixel ----
    const unsigned short* lb = &lx[(row * LROW + c15) * CPAD];
    float* __restrict__ ob = out + (size_t)b * Cc * HWsz + (size_t)(y0 + row) * Ww + (x0 + c15);
    #pragma unroll 2
    for (int cg = 0; cg < 6; ++cg) {
        const int c0 = chh * 48 + cg * 8;
        uint4 tp[9];
        #pragma unroll
        for (int k = 0; k < 9; ++k) {
            const int dy = k / 3, dx = k - 3 * dy;
            tp[k] = *reinterpret_cast<const uint4*>(&lb[(dy*LROW + dx)*CPAD + c0]);
        }
        #pragma unroll
        for (int l = 0; l < 4; ++l) {
            h2 a0 = u2h(GETW(tp[0], l)) * kwp[0];
            h2 a1 = u2h(GETW(tp[1], l)) * kwp[1];
            h2 a2 = u2h(GETW(tp[2], l)) * kwp[2];
            a0 = __builtin_elementwise_fma(u2h(GETW(tp[3], l)), kwp[3], a0);
            a1 = __builtin_elementwise_fma(u2h(GETW(tp[4], l)), kwp[4], a1);
            a2 = __builtin_elementwise_fma(u2h(GETW(tp[5], l)), kwp[5], a2);
            a0 = __builtin_elementwise_fma(u2h(GETW(tp[6], l)), kwp[6], a0);
            a1 = __builtin_elementwise_fma(u2h(GETW(tp[7], l)), kwp[7], a1);
            a2 = __builtin_elementwise_fma(u2h(GETW(tp[8], l)), kwp[8], a2);
            float olo = (float)a0.x + (float)a1.x + (float)a2.x;
            float ohi = (float)a0.y + (float)a1.y + (float)a2.y;
            ob[(size_t)(c0 + 2*l)     * HWsz] = olo;
            ob[(size_t)(c0 + 2*l + 1) * HWsz] = ohi;
        }
    }
}

extern "C" void kernel_launch(void* const* d_in, const int* in_sizes, int n_in,
                              void* d_out, int out_size, void* d_ws, size_t ws_size,
                              hipStream_t stream)
{
    const float* x     = (const float*)d_in[0];
    const float* dw_w  = (const float*)d_in[1];
    const float* dw_b  = (const float*)d_in[2];
    const float* pw1_w = (const float*)d_in[3];
    const float* pw1_b = (const float*)d_in[4];
    const float* pw2_w = (const float*)d_in[5];
    const float* pw2_b = (const float*)d_in[6];
    float* outp = (float*)d_out;
    unsigned* wpk = (unsigned*)d_ws;

    alpf_prep<<<(NPK + 255) / 256, 256, 0, stream>>>(dw_w, dw_b, pw1_w, pw1_b, pw2_w, wpk);

    const int B = in_sizes[0] / (Cc * HWsz);   // 8
    dim3 grid((Ww / TW) * (Hh / TH) * B);      // 1024 tiles, 1D for swizzle control
    alpf_fused<<<grid, 256, 0, stream>>>(x, pw2_b, wpk, outp);
}

// Round 13
// 36.298 us; speedup vs baseline: 1.7487x; 1.7487x over previous
//
#include <hip/hip_runtime.h>
#include <math.h>

#define Cc 96
#define Hh 128
#define Ww 128
#define HWsz (Hh*Ww)
#define TW 16
#define TH 8
#define LROW 18
#define LPLANE 180
#define CPAD 104      // ushort stride per position: 208B rows, 16B-aligned
#define LXSZ (LPLANE * CPAD)

typedef _Float16 h2 __attribute__((ext_vector_type(2)));
typedef short    s8v __attribute__((ext_vector_type(8)));   // 8 bf16 (MFMA A/B frag)
typedef float    f4v __attribute__((ext_vector_type(4)));   // MFMA C/D frag

__device__ __forceinline__ unsigned pkrtz_u(float a, float b) {
    return __builtin_bit_cast(unsigned, __builtin_amdgcn_cvt_pkrtz(a, b));
}
__device__ __forceinline__ h2 pk2(float a, float b) {
    return __builtin_bit_cast(h2, __builtin_amdgcn_cvt_pkrtz(a, b));
}
__device__ __forceinline__ h2 u2h(unsigned u) { return __builtin_bit_cast(h2, u); }
__device__ __forceinline__ unsigned cvt_pk_bf16(float lo, float hi) {
    unsigned r;
    asm("v_cvt_pk_bf16_f32 %0, %1, %2" : "=v"(r) : "v"(lo), "v"(hi));
    return r;
}

__host__ __device__ __forceinline__ unsigned f2bf(float f) {   // fp32 -> bf16 RNE
    unsigned u = __float_as_uint(f);
    return (u + 0x7fffu + ((u >> 16) & 1u)) >> 16;
}

#define GETW(v, wi) ((wi)==0 ? (v).x : (wi)==1 ? (v).y : (wi)==2 ? (v).z : (v).w)

// ---- d_ws layout (dword offsets) ----
#define OFF_WDW 0
#define OFF_W2  480
#define OFF_P1B 704
#define OFF_A   768
#define NPK     3072
#define WLDS_N  752

__global__ void alpf_prep(const float* __restrict__ dw_w, const float* __restrict__ dw_b,
                          const float* __restrict__ pw1_w, const float* __restrict__ pw1_b,
                          const float* __restrict__ pw2_w, unsigned* __restrict__ wpk)
{
    int i = blockIdx.x * 256 + threadIdx.x;
    if (i >= NPK) return;
    unsigned v = 0u;
    if (i < OFF_W2) {
        int g = i / 120, rem = i % 120, ks = rem / 40, s = rem % 40;
        int chb = 32*ks + 8*g;
        if (s < 4) v = pkrtz_u(dw_b[chb + 2*s], dw_b[chb + 2*s + 1]);
        else { int t = (s - 4) / 4, d = (s - 4) % 4;
               v = pkrtz_u(dw_w[(chb + 2*d)*9 + t], dw_w[(chb + 2*d + 1)*9 + t]); }
    } else if (i < OFF_P1B) {
        int idx = i - OFF_W2; int g = idx / 56, s = idx % 56;
        if (s < 54) { int k = s / 6, mm = s % 6, m = mm / 2, rp = mm % 2;
            int o = 16*m + 4*g + 2*rp;
            v = pkrtz_u(pw2_w[k*48 + o], pw2_w[k*48 + o + 1]); }
    } else if (i < OFF_P1B + 48) {
        v = __float_as_uint(pw1_b[i - OFF_P1B]);
    } else if (i >= OFF_A) {
        int idx = i - OFF_A; int f = idx / 256, rem = idx % 256, l = rem / 4, d = rem % 4;
        int m = f / 3, ks = f % 3;
        int o  = 16*m + (l & 15);
        int ch = 32*ks + 8*(l >> 4) + 2*d;
        v = f2bf(pw1_w[o*Cc + ch]) | (f2bf(pw1_w[o*Cc + ch + 1]) << 16);
    }
    wpk[i] = v;
}

__global__ __launch_bounds__(256, 2)
void alpf_fused(const float* __restrict__ x,
                const float* __restrict__ pw2_b,
                const unsigned* __restrict__ wpk,
                float* __restrict__ out)
{
    __shared__ unsigned short lx[2][LXSZ];         // 2 x 37440 B (tile A, tile B)
    __shared__ unsigned wlds[WLDS_N];              // 3008 B weight cache

    const int tid = threadIdx.x;

    // ---- XCD-chunked swizzle: 512 blocks, each XCD owns one batch image ----
    const int nwg   = gridDim.x;            // 512
    const int chunk = nwg >> 3;             // 64
    const int logical = (blockIdx.x & 7) * chunk + (blockIdx.x >> 3);
    const int tx = logical & 7;             // 8 tiles in x
    const int tq = (logical >> 3) & 7;      // 8 vertical tile-pairs
    const int b  = logical >> 6;            // batch image
    const int x0  = tx * TW;
    const int y0A = 2 * tq * TH;
    const int y0B = y0A + TH;
    const float* __restrict__ xb = x + (size_t)b * Cc * HWsz;

    // ---- weight cache copy (752 dwords = 188 uint4) ----
    if (tid < 188)
        *reinterpret_cast<uint4*>(&wlds[tid * 4]) =
            *reinterpret_cast<const uint4*>(wpk + tid * 4);

    const int lane = tid & 63;
    const int g    = lane >> 4;
    const int c15  = lane & 15;
    const int wv   = tid >> 6;              // 0..3
    const int nn   = (lane >> 4) & 1;       // pass-2 row within pair
    const int chh  = lane >> 5;             // pass-2 channel half

    // ---- resident W1 A-fragments (36 VGPRs) ----
    s8v Af[9];
    #pragma unroll
    for (int f = 0; f < 9; ++f)
        Af[f] = __builtin_bit_cast(s8v,
            *reinterpret_cast<const uint4*>(wpk + OFF_A + (f*64 + lane)*4));

    // ---- staging task helpers: task u in [0,960) = (row ri, ch-pair cp, x-half ph) ----
    auto ldtask = [&](int u, int y0, float4& a0, float4& a1, float4& b0, float4& b1,
                      float& ea, float& eb) {
        const int ri  = u / 96;
        const int rem = u - ri * 96;
        const int cp  = rem >> 1;
        const int ph  = rem & 1;
        const int gy  = y0 - 1 + ri;
        const bool okr = (gy >= 0) & (gy < Hh);
        const int gyc = okr ? gy : 0;
        const int chA = 2 * cp;
        const float* pA = xb + (size_t)chA * HWsz + gyc * Ww + x0 + 8 * ph;
        const float* pB = pA + HWsz;
        a0 = *reinterpret_cast<const float4*>(pA);
        a1 = *reinterpret_cast<const float4*>(pA + 4);
        b0 = *reinterpret_cast<const float4*>(pB);
        b1 = *reinterpret_cast<const float4*>(pB + 4);
        if (!okr) { a0 = make_float4(0,0,0,0); a1 = a0; b0 = a0; b1 = a0; }
        const int ecol  = ph ? (x0 + 16) : (x0 - 1);
        const bool oke  = okr & (ecol >= 0) & (ecol < Ww);
        const int ecolc = (ecol >= 0 && ecol < Ww) ? ecol : 0;
        const float* pE = xb + (size_t)chA * HWsz + gyc * Ww + ecolc;
        ea = pE[0]; eb = pE[HWsz];
        if (!oke) { ea = 0.f; eb = 0.f; }
    };
    auto wrtask = [&](int buf, int u, const float4& a0, const float4& a1,
                      const float4& b0, const float4& b1, float ea, float eb) {
        const int ri  = u / 96;
        const int rem = u - ri * 96;
        const int cp  = rem >> 1;
        const int ph  = rem & 1;
        const int chA = 2 * cp;
        const int prow = ri * LROW + 1 + 8 * ph;
        #define STG(q, va, vb) \
            *reinterpret_cast<unsigned*>(&lx[buf][(prow + (q)) * CPAD + chA]) = pkrtz_u(va, vb)
        STG(0, a0.x, b0.x); STG(1, a0.y, b0.y); STG(2, a0.z, b0.z); STG(3, a0.w, b0.w);
        STG(4, a1.x, b1.x); STG(5, a1.y, b1.y); STG(6, a1.z, b1.z); STG(7, a1.w, b1.w);
        #undef STG
        const int eq = ri * LROW + (ph ? 17 : 0);
        *reinterpret_cast<unsigned*>(&lx[buf][eq * CPAD + chA]) = pkrtz_u(ea, eb);
    };

    // ---- kernel-predictor pipeline on one staged tile -> per-thread kwp[9] ----
    auto compute_kw = [&](const unsigned short* lxb, h2* kwp) {
        f4v acc[3][2];
        #pragma unroll
        for (int m = 0; m < 3; ++m) {
            const f4v bb = *reinterpret_cast<const f4v*>(&wlds[OFF_P1B + 16*m + 4*g]);
            acc[m][0] = bb;
            acc[m][1] = bb;
        }
        #pragma unroll
        for (int ks = 0; ks < 3; ++ks) {
            const int base = (g*3 + ks) * 40;
            const uint4 wb = *reinterpret_cast<const uint4*>(&wlds[base]);
            uint4 wt[9];
            #pragma unroll
            for (int t = 0; t < 9; ++t)
                wt[t] = *reinterpret_cast<const uint4*>(&wlds[base + 4 + 4*t]);
            #pragma unroll
            for (int n = 0; n < 2; ++n) {
                h2 b0 = u2h(wb.x), b1 = u2h(wb.y), b2 = u2h(wb.z), b3 = u2h(wb.w);
                #pragma unroll
                for (int t = 0; t < 9; ++t) {
                    const int dy = t / 3, dx = t - 3*dy;
                    const uint4 xv = *reinterpret_cast<const uint4*>(
                        &lxb[((2*wv + n + dy)*LROW + c15 + dx)*CPAD + 32*ks + 8*g]);
                    b0 = __builtin_elementwise_fma(u2h(xv.x), u2h(wt[t].x), b0);
                    b1 = __builtin_elementwise_fma(u2h(xv.y), u2h(wt[t].y), b1);
                    b2 = __builtin_elementwise_fma(u2h(xv.z), u2h(wt[t].z), b2);
                    b3 = __builtin_elementwise_fma(u2h(xv.w), u2h(wt[t].w), b3);
                }
                uint4 bq;
                bq.x = cvt_pk_bf16((float)b0.x, (float)b0.y);
                bq.y = cvt_pk_bf16((float)b1.x, (float)b1.y);
                bq.z = cvt_pk_bf16((float)b2.x, (float)b2.y);
                bq.w = cvt_pk_bf16((float)b3.x, (float)b3.y);
                const s8v Bf = __builtin_bit_cast(s8v, bq);
                acc[0][n] = __builtin_amdgcn_mfma_f32_16x16x32_bf16(Af[0 + ks], Bf, acc[0][n], 0, 0, 0);
                acc[1][n] = __builtin_amdgcn_mfma_f32_16x16x32_bf16(Af[3 + ks], Bf, acc[1][n], 0, 0, 0);
                acc[2][n] = __builtin_amdgcn_mfma_f32_16x16x32_bf16(Af[6 + ks], Bf, acc[2][n], 0, 0, 0);
            }
        }
        h2 tpk[2][3][2];
        #pragma unroll
        for (int n = 0; n < 2; ++n)
            #pragma unroll
            for (int m = 0; m < 3; ++m)
                #pragma unroll
                for (int rp = 0; rp < 2; ++rp) {
                    float a = acc[m][n][2*rp], c = acc[m][n][2*rp + 1];
                    a = (a >= 0.f) ? a : 0.2f * a;
                    c = (c >= 0.f) ? c : 0.2f * c;
                    tpk[n][m][rp] = pk2(a, c);
                }
        uint4 w2q[14];
        #pragma unroll
        for (int j = 0; j < 14; ++j)
            w2q[j] = *reinterpret_cast<const uint4*>(&wlds[OFF_W2 + g*56 + 4*j]);
        float kwr[2][9];
        #pragma unroll
        for (int k = 0; k < 9; ++k) {
            #pragma unroll
            for (int n = 0; n < 2; ++n) {
                h2 s = pk2(0.f, 0.f);
                #pragma unroll
                for (int m = 0; m < 3; ++m)
                    #pragma unroll
                    for (int rp = 0; rp < 2; ++rp) {
                        const int d = k*6 + 2*m + rp;
                        s = __builtin_elementwise_fma(tpk[n][m][rp],
                                                      u2h(GETW(w2q[d >> 2], d & 3)), s);
                    }
                kwr[n][k] = (float)s.x + (float)s.y;
            }
        }
        float kw[9];
        #pragma unroll
        for (int k = 0; k < 9; ++k) {
            float v0 = kwr[0][k];
            v0 += __shfl_xor(v0, 16);
            v0 += __shfl_xor(v0, 32);
            float v1 = kwr[1][k];
            v1 += __shfl_xor(v1, 16);
            v1 += __shfl_xor(v1, 32);
            kw[k] = (nn ? v1 : v0) + pw2_b[k];
        }
        float mx = kw[0];
        #pragma unroll
        for (int k = 1; k < 9; ++k) mx = fmaxf(mx, kw[k]);
        float sum = 0.f;
        #pragma unroll
        for (int k = 0; k < 9; ++k) { kw[k] = __expf(kw[k] - mx); sum += kw[k]; }
        const float inv = 1.f / sum;
        #pragma unroll
        for (int k = 0; k < 9; ++k) kwp[k] = pk2(kw[k] * inv, kw[k] * inv);
    };

    // ---- smoothing pass over cg range [cg0, cg1) ----
    auto smooth = [&](const unsigned short* lxb, const h2* kwp, int y0, int cg0, int cg1) {
        const int row = 2*wv + nn;
        const unsigned short* lb = &lxb[(row * LROW + c15) * CPAD];
        float* __restrict__ ob = out + (size_t)b * Cc * HWsz
                                     + (size_t)(y0 + row) * Ww + (x0 + c15);
        for (int cg = cg0; cg < cg1; ++cg) {
            const int c0 = chh * 48 + cg * 8;
            uint4 tp[9];
            #pragma unroll
            for (int k = 0; k < 9; ++k) {
                const int dy = k / 3, dx = k - 3 * dy;
                tp[k] = *reinterpret_cast<const uint4*>(&lb[(dy*LROW + dx)*CPAD + c0]);
            }
            #pragma unroll
            for (int l = 0; l < 4; ++l) {
                h2 a0 = u2h(GETW(tp[0], l)) * kwp[0];
                h2 a1 = u2h(GETW(tp[1], l)) * kwp[1];
                h2 a2 = u2h(GETW(tp[2], l)) * kwp[2];
                a0 = __builtin_elementwise_fma(u2h(GETW(tp[3], l)), kwp[3], a0);
                a1 = __builtin_elementwise_fma(u2h(GETW(tp[4], l)), kwp[4], a1);
                a2 = __builtin_elementwise_fma(u2h(GETW(tp[5], l)), kwp[5], a2);
                a0 = __builtin_elementwise_fma(u2h(GETW(tp[6], l)), kwp[6], a0);
                a1 = __builtin_elementwise_fma(u2h(GETW(tp[7], l)), kwp[7], a1);
                a2 = __builtin_elementwise_fma(u2h(GETW(tp[8], l)), kwp[8], a2);
                float olo = (float)a0.x + (float)a1.x + (float)a2.x;
                float ohi = (float)a0.y + (float)a1.y + (float)a2.y;
                ob[(size_t)(c0 + 2*l)     * HWsz] = olo;
                ob[(size_t)(c0 + 2*l + 1) * HWsz] = ohi;
            }
        }
    };

    // ---- stage tile A (monolithic, all blocks phase-aligned) ----
    #pragma unroll
    for (int i = 0; i < 4; ++i) {
        const int u = tid + 256*i;
        if (u < 960) {
            float4 a0,a1,b0,b1; float ea,eb;
            ldtask(u, y0A, a0,a1,b0,b1, ea,eb);
            wrtask(0, u, a0,a1,b0,b1, ea,eb);
        }
    }
    __syncthreads();

    h2 kwpA[9];
    compute_kw(&lx[0][0], kwpA);

    // ---- overlap phase: B reads ride under A writes (two half-phases) ----
    {
        float4 st[2][4]; float se[2][2];
        // half 1: issue B loads (tasks 0,1) -> A smooth cg 0..2 -> B writes
        #pragma unroll
        for (int i = 0; i < 2; ++i)
            ldtask(tid + 256*i, y0B, st[i][0], st[i][1], st[i][2], st[i][3],
                   se[i][0], se[i][1]);
        smooth(&lx[0][0], kwpA, y0A, 0, 3);
        #pragma unroll
        for (int i = 0; i < 2; ++i)
            wrtask(1, tid + 256*i, st[i][0], st[i][1], st[i][2], st[i][3],
                   se[i][0], se[i][1]);
        // half 2: issue B loads (tasks 2,3) -> A smooth cg 3..5 -> B writes
        #pragma unroll
        for (int i = 0; i < 2; ++i) {
            const int u = tid + 256*(i + 2);
            if (u < 960) ldtask(u, y0B, st[i][0], st[i][1], st[i][2], st[i][3],
                                se[i][0], se[i][1]);
        }
        smooth(&lx[0][0], kwpA, y0A, 3, 6);
        #pragma unroll
        for (int i = 0; i < 2; ++i) {
            const int u = tid + 256*(i + 2);
            if (u < 960) wrtask(1, u, st[i][0], st[i][1], st[i][2], st[i][3],
                                se[i][0], se[i][1]);
        }
    }
    __syncthreads();

    // ---- tile B ----
    h2 kwpB[9];
    compute_kw(&lx[1][0], kwpB);
    smooth(&lx[1][0], kwpB, y0B, 0, 6);
}

extern "C" void kernel_launch(void* const* d_in, const int* in_sizes, int n_in,
                              void* d_out, int out_size, void* d_ws, size_t ws_size,
                              hipStream_t stream)
{
    const float* x     = (const float*)d_in[0];
    const float* dw_w  = (const float*)d_in[1];
    const float* dw_b  = (const float*)d_in[2];
    const float* pw1_w = (const float*)d_in[3];
    const float* pw1_b = (const float*)d_in[4];
    const float* pw2_w = (const float*)d_in[5];
    const float* pw2_b = (const float*)d_in[6];
    float* outp = (float*)d_out;
    unsigned* wpk = (unsigned*)d_ws;

    alpf_prep<<<(NPK + 255) / 256, 256, 0, stream>>>(dw_w, dw_b, pw1_w, pw1_b, pw2_w, wpk);

    const int B = in_sizes[0] / (Cc * HWsz);   // 8
    dim3 grid((Ww / TW) * (Hh / (2 * TH)) * B);   // 512 blocks, 2 tiles each
    alpf_fused<<<grid, 256, 0, stream>>>(x, pw2_b, wpk, outp);
}